// Round 2
// baseline (2372.250 us; speedup 1.0000x reference)
//
#include <hip/hip_runtime.h>
#include <hip/hip_bf16.h>
#include <math.h>

#define NQ 30000
#define NS 400
#define DD 128
#define HH 128
#define SS 200
#define BB 256
#define MSq 4
#define MBs 4
#define PP 512
#define SB (SS*BB)      // 51200
#define G3 384          // 3*H
#define QPB 16

typedef __hip_bfloat16 bf16;

__device__ __forceinline__ float sigf(float x){ return 1.0f/(1.0f+expf(-x)); }
__device__ __forceinline__ float bf2f(unsigned short u){
  unsigned int x = ((unsigned int)u)<<16;
  return __uint_as_float(x);
}

// ---------------- tables: T_ans = ans_emb @ Wi[:,0:128].T etc ----------------
__global__ __launch_bounds__(128) void tables_k(const float* __restrict__ ans_emb,
        const float* __restrict__ label_emb, const float* __restrict__ Wi,
        float* __restrict__ Tans, float* __restrict__ Tcae, float* __restrict__ Tlab){
  int j = blockIdx.x*128 + threadIdx.x;
  if (j >= G3) return;
  const float* wr = Wi + (size_t)j*640;
  for (int a=0;a<4;a++){
    float acc=0.f;
    for (int k=0;k<DD;k++) acc += ans_emb[a*DD+k]*wr[k];
    Tans[a*G3+j]=acc;
  }
  for (int a=0;a<4;a++){
    float acc=0.f;
    for (int k=0;k<DD;k++) acc += ans_emb[a*DD+k]*wr[128+k];
    Tcae[a*G3+j]=acc;
  }
  for (int l=0;l<2;l++){
    float acc=0.f;
    for (int k=0;k<DD;k++) acc += label_emb[l*DD+k]*wr[256+k];
    Tlab[l*G3+j]=acc;
  }
}

// ---------------- q2s projection + scatter to subject sums ----------------
__global__ __launch_bounds__(128) void q2s_scatter(const float* __restrict__ q_emb,
        const float* __restrict__ W, const float* __restrict__ bias,
        const int* __restrict__ q_map, float* __restrict__ sums, float* __restrict__ cnts){
  __shared__ float qe[QPB][DD];
  int q0 = blockIdx.x*QPB;
  int tid = threadIdx.x;
  for (int r=0;r<QPB;r++) qe[r][tid] = q_emb[(size_t)(q0+r)*DD + tid];
  __syncthreads();
  float acc[QPB];
  #pragma unroll
  for (int r=0;r<QPB;r++) acc[r] = bias[tid];
  const float4* wr = (const float4*)(W + (size_t)tid*DD);
  #pragma unroll 4
  for (int k4=0;k4<DD/4;k4++){
    float4 w = wr[k4];
    #pragma unroll
    for (int r=0;r<QPB;r++){
      acc[r] += w.x*qe[r][k4*4] + w.y*qe[r][k4*4+1] + w.z*qe[r][k4*4+2] + w.w*qe[r][k4*4+3];
    }
  }
  for (int r=0;r<QPB;r++){
    int q = q0+r;
    #pragma unroll
    for (int m=0;m<MSq;m++){
      int s = q_map[q*MSq+m];
      atomicAdd(&sums[(size_t)s*DD + tid], acc[r]);
      if (tid==0) atomicAdd(&cnts[s], 1.0f);
    }
  }
}

// ---------------- subjects_1 ----------------
__global__ __launch_bounds__(128) void subjects1_k(const float* __restrict__ s_emb,
        const float* __restrict__ W, const float* __restrict__ bias,
        const float* __restrict__ sums, const float* __restrict__ cnts,
        float* __restrict__ out){
  __shared__ float se[DD];
  int s = blockIdx.x; int tid = threadIdx.x;
  se[tid] = s_emb[(size_t)s*DD+tid];
  __syncthreads();
  float acc = bias[tid];
  const float4* wr = (const float4*)(W + (size_t)tid*DD);
  for (int k4=0;k4<DD/4;k4++){
    float4 w = wr[k4];
    acc += w.x*se[k4*4] + w.y*se[k4*4+1] + w.z*se[k4*4+2] + w.w*se[k4*4+3];
  }
  float c = cnts[s];
  float v = 0.f;
  if (c > 0.f) v = tanhf(sums[(size_t)s*DD+tid]/fmaxf(c,1.f) + acc);
  out[(size_t)s*DD+tid] = v;
}

// ---------------- questions_1 (bf16 out) ----------------
__global__ __launch_bounds__(128) void questions1_k(const float* __restrict__ q_emb,
        const float* __restrict__ subj1, const int* __restrict__ q_map,
        const float* __restrict__ q_mask,
        const float* __restrict__ s2qW, const float* __restrict__ s2qb,
        const float* __restrict__ q2qW, const float* __restrict__ q2qb,
        bf16* __restrict__ q1out){
  __shared__ float qe[QPB][DD];
  __shared__ float nq[QPB][DD];
  int q0 = blockIdx.x*QPB; int tid = threadIdx.x;
  for (int r=0;r<QPB;r++){
    int q = q0+r;
    qe[r][tid] = q_emb[(size_t)q*DD+tid];
    float sum=0.f, wsum=0.f;
    #pragma unroll
    for (int m=0;m<MSq;m++){
      float w = q_mask[q*MSq+m];
      sum += subj1[(size_t)q_map[q*MSq+m]*DD + tid]*w;
      wsum += w;
    }
    nq[r][tid] = sum / wsum;
  }
  __syncthreads();
  float acc[QPB];
  #pragma unroll
  for (int r=0;r<QPB;r++) acc[r] = s2qb[tid]+q2qb[tid];
  const float4* w1 = (const float4*)(s2qW + (size_t)tid*DD);
  const float4* w2 = (const float4*)(q2qW + (size_t)tid*DD);
  #pragma unroll 2
  for (int k4=0;k4<DD/4;k4++){
    float4 a = w1[k4]; float4 b = w2[k4];
    #pragma unroll
    for (int r=0;r<QPB;r++){
      acc[r] += a.x*nq[r][k4*4] + a.y*nq[r][k4*4+1] + a.z*nq[r][k4*4+2] + a.w*nq[r][k4*4+3]
              + b.x*qe[r][k4*4] + b.y*qe[r][k4*4+1] + b.z*qe[r][k4*4+2] + b.w*qe[r][k4*4+3];
    }
  }
  for (int r=0;r<QPB;r++) q1out[(size_t)(q0+r)*DD+tid] = __float2bfloat16(tanhf(acc[r]));
}

// ---------------- assemble pred_input cols 0:256 and 384:512 (bf16) ----------------
__global__ __launch_bounds__(128) void assemble_k(const bf16* __restrict__ q1,
        const float* __restrict__ subj1, const float* __restrict__ ans_emb,
        const int* __restrict__ cans, const int* __restrict__ sub_ids,
        const float* __restrict__ sub_mask, const int* __restrict__ q_ids,
        bf16* __restrict__ pred){
  int i = blockIdx.x; int d = threadIdx.x;
  size_t base = (size_t)i*PP;
  pred[base + d] = q1[(size_t)q_ids[i]*DD + d];
  float s = 0.f;
  #pragma unroll
  for (int m=0;m<MBs;m++)
    s += subj1[(size_t)sub_ids[i*MBs+m]*DD+d]*sub_mask[i*MBs+m];
  pred[base+128+d] = __float2bfloat16(s);
  pred[base+384+d] = __float2bfloat16(ans_emb[(size_t)cans[i]*DD + d]);
}

// ---- shared GEMM tile core: A bf16 row-major, B f32 row-major; 128x128 tile ----
__device__ __forceinline__ void gemm_tile_bA(const bf16* __restrict__ A, int lda,
        const float* __restrict__ Bm, int ldb, int K, int m0, int n0,
        float (*As)[132], float (*Bs)[132], float acc[8][8]){
  const int tid = threadIdx.x;
  const int tx = tid & 15, ty = tid >> 4;
  const int lrow = tid >> 1;
  const int lk0 = (tid & 1) * 8;
  for (int kt = 0; kt < K; kt += 16){
    __syncthreads();
    uint4 av = *(const uint4*)(A + (size_t)(m0+lrow)*lda + kt + lk0);
    unsigned int aw0=av.x, aw1=av.y, aw2=av.z, aw3=av.w;
    As[lk0+0][lrow]=bf2f((unsigned short)(aw0&0xffff));
    As[lk0+1][lrow]=bf2f((unsigned short)(aw0>>16));
    As[lk0+2][lrow]=bf2f((unsigned short)(aw1&0xffff));
    As[lk0+3][lrow]=bf2f((unsigned short)(aw1>>16));
    As[lk0+4][lrow]=bf2f((unsigned short)(aw2&0xffff));
    As[lk0+5][lrow]=bf2f((unsigned short)(aw2>>16));
    As[lk0+6][lrow]=bf2f((unsigned short)(aw3&0xffff));
    As[lk0+7][lrow]=bf2f((unsigned short)(aw3>>16));
    #pragma unroll
    for (int l=0;l<2;l++){
      int k = lk0 + l*4;
      float4 bv = *(const float4*)(Bm + (size_t)(n0+lrow)*ldb + kt + k);
      Bs[k+0][lrow]=bv.x; Bs[k+1][lrow]=bv.y; Bs[k+2][lrow]=bv.z; Bs[k+3][lrow]=bv.w;
    }
    __syncthreads();
    #pragma unroll
    for (int kk=0;kk<16;kk++){
      float4 a0 = *(const float4*)(&As[kk][ty*8]);
      float4 a1 = *(const float4*)(&As[kk][ty*8+4]);
      float4 b0 = *(const float4*)(&Bs[kk][tx*8]);
      float4 b1 = *(const float4*)(&Bs[kk][tx*8+4]);
      float a[8] = {a0.x,a0.y,a0.z,a0.w,a1.x,a1.y,a1.z,a1.w};
      float b[8] = {b0.x,b0.y,b0.z,b0.w,b1.x,b1.y,b1.z,b1.w};
      #pragma unroll
      for (int i=0;i<8;i++)
        #pragma unroll
        for (int j=0;j<8;j++)
          acc[i][j] += a[i]*b[j];
    }
  }
  __syncthreads();
}

// ---------------- xp = [Q,Sub]@Wi[:,384:640].T + tables + bi ----------------
__global__ __launch_bounds__(256) void gemm_xp(const bf16* __restrict__ pred,
        const float* __restrict__ Wi, const float* __restrict__ bi,
        const float* __restrict__ Tans, const float* __restrict__ Tcae,
        const float* __restrict__ Tlab,
        const float* __restrict__ tm, const float* __restrict__ vm,
        const float* __restrict__ lm,
        const int* __restrict__ ans, const int* __restrict__ cans,
        const float* __restrict__ labels, float* __restrict__ xp){
  __shared__ float As[16][132]; __shared__ float Bs[16][132];
  float acc[8][8] = {{0.f}};
  int m0 = blockIdx.y*128, n0 = blockIdx.x*128;
  gemm_tile_bA(pred, PP, Wi+384, 640, 256, m0, n0, As, Bs, acc);
  int tx = threadIdx.x&15, ty = threadIdx.x>>4;
  #pragma unroll
  for (int i=0;i<8;i++){
    int r = m0 + ty*8 + i;
    float mk = tm[r]*vm[r]*lm[r];
    int a = ans[r], ca = cans[r], lb = (int)labels[r];
    #pragma unroll
    for (int j=0;j<8;j++){
      int c = n0 + tx*8 + j;
      xp[(size_t)r*G3 + c] = acc[i][j] + bi[c] + mk*Tans[a*G3+c] + Tcae[ca*G3+c] + mk*Tlab[lb*G3+c];
    }
  }
}

// ---------------- GRU scan: one block per batch element ----------------
__global__ __launch_bounds__(384) void gru_scan(const float* __restrict__ xp,
        const float* __restrict__ Wh, const float* __restrict__ bh,
        bf16* __restrict__ pred){
  __shared__ float hs[HH];
  __shared__ float gh[G3];
  int b = blockIdx.x;
  int tid = threadIdx.x;
  if (tid < HH) hs[tid] = 0.f;
  __syncthreads();
  const float4* wr = (const float4*)(Wh + (size_t)tid*HH);
  float bhv = bh[tid];
  for (int t=0;t<SS;t++){
    float acc = bhv;
    #pragma unroll 8
    for (int k4=0;k4<HH/4;k4++){
      float4 w = wr[k4];
      acc += w.x*hs[k4*4] + w.y*hs[k4*4+1] + w.z*hs[k4*4+2] + w.w*hs[k4*4+3];
    }
    gh[tid] = acc;
    __syncthreads();
    if (tid < HH){
      const float* xrow = xp + (size_t)(t*BB + b)*G3;
      float xr = xrow[tid], xz = xrow[HH+tid], xn = xrow[2*HH+tid];
      float hprev = hs[tid];
      float r = sigf(xr + gh[tid]);
      float z = sigf(xz + gh[HH+tid]);
      float n = tanhf(xn + r*gh[2*HH+tid]);
      float hnew = (1.f - z)*n + z*hprev;
      pred[(size_t)(t*BB + b)*PP + 256 + tid] = __float2bfloat16(hprev);
      hs[tid] = hnew;
    }
    __syncthreads();
  }
}

// ---------------- h1 = relu(pred@l1W.T + b) (bf16 out) ----------------
__global__ __launch_bounds__(256) void gemm_l1(const bf16* __restrict__ pred,
        const float* __restrict__ W, const float* __restrict__ bias,
        bf16* __restrict__ h1){
  __shared__ float As[16][132]; __shared__ float Bs[16][132];
  float acc[8][8] = {{0.f}};
  int m0 = blockIdx.y*128, n0 = blockIdx.x*128;
  gemm_tile_bA(pred, PP, W, PP, PP, m0, n0, As, Bs, acc);
  int tx = threadIdx.x&15, ty = threadIdx.x>>4;
  #pragma unroll
  for (int i=0;i<8;i++){
    int r = m0 + ty*8 + i;
    #pragma unroll
    for (int j=0;j<8;j++){
      int c = n0 + tx*8 + j;
      h1[(size_t)r*PP + c] = __float2bfloat16(fmaxf(acc[i][j] + bias[c], 0.f));
    }
  }
}

// ---------------- h2 tile + fused (h2+pred)@outW partial into logits ----------------
__global__ __launch_bounds__(256) void gemm_l2_logits(const bf16* __restrict__ h1,
        const float* __restrict__ W, const float* __restrict__ bias,
        const bf16* __restrict__ pred, const float* __restrict__ outW,
        float* __restrict__ logits){
  __shared__ float As[16][132]; __shared__ float Bs[16][132];
  float acc[8][8] = {{0.f}};
  int m0 = blockIdx.y*128, n0 = blockIdx.x*128;
  gemm_tile_bA(h1, PP, W, PP, PP, m0, n0, As, Bs, acc);
  int tx = threadIdx.x&15, ty = threadIdx.x>>4;
  #pragma unroll
  for (int i=0;i<8;i++){
    int r = m0 + ty*8 + i;
    float part = 0.f;
    #pragma unroll
    for (int j=0;j<8;j++){
      int c = n0 + tx*8 + j;
      float h2v = fmaxf(acc[i][j] + bias[c], 0.f);
      part += (h2v + __bfloat162float(pred[(size_t)r*PP+c]))*outW[c];
    }
    part += __shfl_xor(part,1);
    part += __shfl_xor(part,2);
    part += __shfl_xor(part,4);
    part += __shfl_xor(part,8);
    if (tx==0) atomicAdd(&logits[r], part);
  }
}

// ---------------- loss + probs ----------------
__global__ __launch_bounds__(256) void loss_probs_k(const float* __restrict__ logits,
        const float* __restrict__ labels, const float* __restrict__ tm,
        const float* __restrict__ vm, const float* __restrict__ lm,
        const float* __restrict__ out_b, float* __restrict__ out,
        float* __restrict__ lacc){
  int i = blockIdx.x*256 + threadIdx.x;
  float x = logits[i] + out_b[0];
  float lb = labels[i];
  float mk = tm[i]*vm[i]*lm[i];
  float sp = fmaxf(x,0.f) + log1pf(expf(-fabsf(x)));
  float pe = (sp - x*lb)*mk;
  out[1+i] = sigf(x);
  float v0 = pe, v1 = mk;
  for (int o=32;o>0;o>>=1){ v0 += __shfl_down(v0,o); v1 += __shfl_down(v1,o); }
  if ((threadIdx.x & 63)==0){ atomicAdd(&lacc[0], v0); atomicAdd(&lacc[1], v1); }
}

__global__ void finalize_k(const float* __restrict__ lacc, float* __restrict__ out){
  out[0] = lacc[0]/lacc[1];
}

// ---------------- launch ----------------
extern "C" void kernel_launch(void* const* d_in, const int* in_sizes, int n_in,
                              void* d_out, int out_size, void* d_ws, size_t ws_size,
                              hipStream_t stream) {
  const float* q_emb   = (const float*)d_in[0];
  const float* s_emb   = (const float*)d_in[1];
  const float* ans_emb = (const float*)d_in[2];
  const float* lab_emb = (const float*)d_in[3];
  const float* gru_Wi  = (const float*)d_in[4];
  const float* gru_Wh  = (const float*)d_in[5];
  const float* gru_bi  = (const float*)d_in[6];
  const float* gru_bh  = (const float*)d_in[7];
  const float* s2s_W   = (const float*)d_in[8];
  const float* s2s_b   = (const float*)d_in[9];
  const float* s2q_W   = (const float*)d_in[10];
  const float* s2q_b   = (const float*)d_in[11];
  const float* q2q_W   = (const float*)d_in[12];
  const float* q2q_b   = (const float*)d_in[13];
  const float* q2s_W   = (const float*)d_in[14];
  const float* q2s_b   = (const float*)d_in[15];
  const float* l1_W    = (const float*)d_in[16];
  const float* l1_b    = (const float*)d_in[17];
  const float* l2_W    = (const float*)d_in[18];
  const float* l2_b    = (const float*)d_in[19];
  const float* out_W   = (const float*)d_in[20];
  const float* out_b   = (const float*)d_in[21];
  const float* tm      = (const float*)d_in[22];
  const float* vm      = (const float*)d_in[23];
  const float* lm      = (const float*)d_in[24];
  const float* smask   = (const float*)d_in[25];
  const float* q_mask  = (const float*)d_in[26];
  const float* labels  = (const float*)d_in[27];
  const int*   ans     = (const int*)d_in[28];
  const int*   cans    = (const int*)d_in[29];
  const int*   sub_ids = (const int*)d_in[30];
  const int*   q_ids   = (const int*)d_in[31];
  const int*   q_map   = (const int*)d_in[32];

  // ---- workspace layout (byte offsets, 256B-aligned) ----
  char* wsb = (char*)d_ws;
  size_t off = 0;
  auto alloc = [&](size_t bytes) -> char* {
    char* p = wsb + off;
    off += (bytes + 255) & ~(size_t)255;
    return p;
  };
  float* sums   = (float*)alloc(51200*4);        // [Ns,D]
  float* cnts   = (float*)alloc(400*4);
  float* subj1  = (float*)alloc(51200*4);        // [Ns,D] f32
  float* Tans   = (float*)alloc(4*G3*4);
  float* Tcae   = (float*)alloc(4*G3*4);
  float* Tlab   = (float*)alloc(2*G3*4);
  float* lacc   = (float*)alloc(2*4);
  float* logits = (float*)alloc((size_t)SB*4);
  bf16*  q1     = (bf16*) alloc((size_t)NQ*DD*2);        // 7.68 MB
  bf16*  pred   = (bf16*) alloc((size_t)SB*PP*2);        // 52.4 MB
  char*  xh     = alloc((size_t)SB*G3*4);                // 78.6 MB: xp f32, then h1 bf16
  float* xp     = (float*)xh;
  bf16*  h1     = (bf16*)xh;   // aliased: xp dead after gru_scan
  float* out    = (float*)d_out;

  hipMemsetAsync(sums, 0, (51200+400)*sizeof(float), stream);
  hipMemsetAsync(lacc, 0, 2*sizeof(float), stream);
  hipMemsetAsync(logits, 0, (size_t)SB*sizeof(float), stream);

  tables_k<<<dim3(3), dim3(128), 0, stream>>>(ans_emb, lab_emb, gru_Wi, Tans, Tcae, Tlab);
  q2s_scatter<<<dim3(NQ/QPB), dim3(128), 0, stream>>>(q_emb, q2s_W, q2s_b, q_map, sums, cnts);
  subjects1_k<<<dim3(NS), dim3(128), 0, stream>>>(s_emb, s2s_W, s2s_b, sums, cnts, subj1);
  questions1_k<<<dim3(NQ/QPB), dim3(128), 0, stream>>>(q_emb, subj1, q_map, q_mask,
                                                       s2q_W, s2q_b, q2q_W, q2q_b, q1);
  assemble_k<<<dim3(SB), dim3(128), 0, stream>>>(q1, subj1, ans_emb, cans, sub_ids, smask, q_ids, pred);
  gemm_xp<<<dim3(3,400), dim3(256), 0, stream>>>(pred, gru_Wi, gru_bi, Tans, Tcae, Tlab,
                                                 tm, vm, lm, ans, cans, labels, xp);
  gru_scan<<<dim3(BB), dim3(384), 0, stream>>>(xp, gru_Wh, gru_bh, pred);
  gemm_l1<<<dim3(4,400), dim3(256), 0, stream>>>(pred, l1_W, l1_b, h1);
  gemm_l2_logits<<<dim3(4,400), dim3(256), 0, stream>>>(h1, l2_W, l2_b, pred, out_W, logits);
  loss_probs_k<<<dim3(SB/256), dim3(256), 0, stream>>>(logits, labels, tm, vm, lm, out_b, out, lacc);
  finalize_k<<<dim3(1), dim3(1), 0, stream>>>(lacc, out);
}

// Round 3
// 1416.822 us; speedup vs baseline: 1.6743x; 1.6743x over previous
//
#include <hip/hip_runtime.h>
#include <hip/hip_bf16.h>
#include <math.h>

#define NQ 30000
#define NS 400
#define DD 128
#define HH 128
#define SS 200
#define BB 256
#define MSq 4
#define MBs 4
#define PP 512
#define SB (SS*BB)      // 51200
#define G3 384          // 3*H
#define QPB 16

typedef __hip_bfloat16 bf16;

__device__ __forceinline__ float sigf(float x){ return 1.0f/(1.0f+expf(-x)); }
__device__ __forceinline__ float bf2f(unsigned short u){
  unsigned int x = ((unsigned int)u)<<16;
  return __uint_as_float(x);
}

// ---------------- tables: T_ans = ans_emb @ Wi[:,0:128].T etc ----------------
__global__ __launch_bounds__(128) void tables_k(const float* __restrict__ ans_emb,
        const float* __restrict__ label_emb, const float* __restrict__ Wi,
        float* __restrict__ Tans, float* __restrict__ Tcae, float* __restrict__ Tlab){
  int j = blockIdx.x*128 + threadIdx.x;
  if (j >= G3) return;
  const float* wr = Wi + (size_t)j*640;
  for (int a=0;a<4;a++){
    float acc=0.f;
    for (int k=0;k<DD;k++) acc += ans_emb[a*DD+k]*wr[k];
    Tans[a*G3+j]=acc;
  }
  for (int a=0;a<4;a++){
    float acc=0.f;
    for (int k=0;k<DD;k++) acc += ans_emb[a*DD+k]*wr[128+k];
    Tcae[a*G3+j]=acc;
  }
  for (int l=0;l<2;l++){
    float acc=0.f;
    for (int k=0;k<DD;k++) acc += label_emb[l*DD+k]*wr[256+k];
    Tlab[l*G3+j]=acc;
  }
}

// ---------------- q2s projection + scatter to subject sums ----------------
__global__ __launch_bounds__(128) void q2s_scatter(const float* __restrict__ q_emb,
        const float* __restrict__ W, const float* __restrict__ bias,
        const int* __restrict__ q_map, float* __restrict__ sums, float* __restrict__ cnts){
  __shared__ float qe[QPB][DD];
  int q0 = blockIdx.x*QPB;
  int tid = threadIdx.x;
  for (int r=0;r<QPB;r++) qe[r][tid] = q_emb[(size_t)(q0+r)*DD + tid];
  __syncthreads();
  float acc[QPB];
  #pragma unroll
  for (int r=0;r<QPB;r++) acc[r] = bias[tid];
  const float4* wr = (const float4*)(W + (size_t)tid*DD);
  #pragma unroll 4
  for (int k4=0;k4<DD/4;k4++){
    float4 w = wr[k4];
    #pragma unroll
    for (int r=0;r<QPB;r++){
      acc[r] += w.x*qe[r][k4*4] + w.y*qe[r][k4*4+1] + w.z*qe[r][k4*4+2] + w.w*qe[r][k4*4+3];
    }
  }
  for (int r=0;r<QPB;r++){
    int q = q0+r;
    #pragma unroll
    for (int m=0;m<MSq;m++){
      int s = q_map[q*MSq+m];
      atomicAdd(&sums[(size_t)s*DD + tid], acc[r]);
      if (tid==0) atomicAdd(&cnts[s], 1.0f);
    }
  }
}

// ---------------- subjects_1 ----------------
__global__ __launch_bounds__(128) void subjects1_k(const float* __restrict__ s_emb,
        const float* __restrict__ W, const float* __restrict__ bias,
        const float* __restrict__ sums, const float* __restrict__ cnts,
        float* __restrict__ out){
  __shared__ float se[DD];
  int s = blockIdx.x; int tid = threadIdx.x;
  se[tid] = s_emb[(size_t)s*DD+tid];
  __syncthreads();
  float acc = bias[tid];
  const float4* wr = (const float4*)(W + (size_t)tid*DD);
  for (int k4=0;k4<DD/4;k4++){
    float4 w = wr[k4];
    acc += w.x*se[k4*4] + w.y*se[k4*4+1] + w.z*se[k4*4+2] + w.w*se[k4*4+3];
  }
  float c = cnts[s];
  float v = 0.f;
  if (c > 0.f) v = tanhf(sums[(size_t)s*DD+tid]/fmaxf(c,1.f) + acc);
  out[(size_t)s*DD+tid] = v;
}

// ---------------- questions_1 (bf16 out) ----------------
__global__ __launch_bounds__(128) void questions1_k(const float* __restrict__ q_emb,
        const float* __restrict__ subj1, const int* __restrict__ q_map,
        const float* __restrict__ q_mask,
        const float* __restrict__ s2qW, const float* __restrict__ s2qb,
        const float* __restrict__ q2qW, const float* __restrict__ q2qb,
        bf16* __restrict__ q1out){
  __shared__ float qe[QPB][DD];
  __shared__ float nq[QPB][DD];
  int q0 = blockIdx.x*QPB; int tid = threadIdx.x;
  for (int r=0;r<QPB;r++){
    int q = q0+r;
    qe[r][tid] = q_emb[(size_t)q*DD+tid];
    float sum=0.f, wsum=0.f;
    #pragma unroll
    for (int m=0;m<MSq;m++){
      float w = q_mask[q*MSq+m];
      sum += subj1[(size_t)q_map[q*MSq+m]*DD + tid]*w;
      wsum += w;
    }
    nq[r][tid] = sum / wsum;
  }
  __syncthreads();
  float acc[QPB];
  #pragma unroll
  for (int r=0;r<QPB;r++) acc[r] = s2qb[tid]+q2qb[tid];
  const float4* w1 = (const float4*)(s2qW + (size_t)tid*DD);
  const float4* w2 = (const float4*)(q2qW + (size_t)tid*DD);
  #pragma unroll 2
  for (int k4=0;k4<DD/4;k4++){
    float4 a = w1[k4]; float4 b = w2[k4];
    #pragma unroll
    for (int r=0;r<QPB;r++){
      acc[r] += a.x*nq[r][k4*4] + a.y*nq[r][k4*4+1] + a.z*nq[r][k4*4+2] + a.w*nq[r][k4*4+3]
              + b.x*qe[r][k4*4] + b.y*qe[r][k4*4+1] + b.z*qe[r][k4*4+2] + b.w*qe[r][k4*4+3];
    }
  }
  for (int r=0;r<QPB;r++) q1out[(size_t)(q0+r)*DD+tid] = __float2bfloat16(tanhf(acc[r]));
}

// ---------------- assemble pred_input cols 0:256 and 384:512 (bf16) ----------------
__global__ __launch_bounds__(128) void assemble_k(const bf16* __restrict__ q1,
        const float* __restrict__ subj1, const float* __restrict__ ans_emb,
        const int* __restrict__ cans, const int* __restrict__ sub_ids,
        const float* __restrict__ sub_mask, const int* __restrict__ q_ids,
        bf16* __restrict__ pred){
  int i = blockIdx.x; int d = threadIdx.x;
  size_t base = (size_t)i*PP;
  pred[base + d] = q1[(size_t)q_ids[i]*DD + d];
  float s = 0.f;
  #pragma unroll
  for (int m=0;m<MBs;m++)
    s += subj1[(size_t)sub_ids[i*MBs+m]*DD+d]*sub_mask[i*MBs+m];
  pred[base+128+d] = __float2bfloat16(s);
  pred[base+384+d] = __float2bfloat16(ans_emb[(size_t)cans[i]*DD + d]);
}

// ---- shared GEMM tile core: A bf16 row-major, B f32 row-major; 128x128 tile ----
__device__ __forceinline__ void gemm_tile_bA(const bf16* __restrict__ A, int lda,
        const float* __restrict__ Bm, int ldb, int K, int m0, int n0,
        float (*As)[132], float (*Bs)[132], float acc[8][8]){
  const int tid = threadIdx.x;
  const int tx = tid & 15, ty = tid >> 4;
  const int lrow = tid >> 1;
  const int lk0 = (tid & 1) * 8;
  for (int kt = 0; kt < K; kt += 16){
    __syncthreads();
    uint4 av = *(const uint4*)(A + (size_t)(m0+lrow)*lda + kt + lk0);
    unsigned int aw0=av.x, aw1=av.y, aw2=av.z, aw3=av.w;
    As[lk0+0][lrow]=bf2f((unsigned short)(aw0&0xffff));
    As[lk0+1][lrow]=bf2f((unsigned short)(aw0>>16));
    As[lk0+2][lrow]=bf2f((unsigned short)(aw1&0xffff));
    As[lk0+3][lrow]=bf2f((unsigned short)(aw1>>16));
    As[lk0+4][lrow]=bf2f((unsigned short)(aw2&0xffff));
    As[lk0+5][lrow]=bf2f((unsigned short)(aw2>>16));
    As[lk0+6][lrow]=bf2f((unsigned short)(aw3&0xffff));
    As[lk0+7][lrow]=bf2f((unsigned short)(aw3>>16));
    #pragma unroll
    for (int l=0;l<2;l++){
      int k = lk0 + l*4;
      float4 bv = *(const float4*)(Bm + (size_t)(n0+lrow)*ldb + kt + k);
      Bs[k+0][lrow]=bv.x; Bs[k+1][lrow]=bv.y; Bs[k+2][lrow]=bv.z; Bs[k+3][lrow]=bv.w;
    }
    __syncthreads();
    #pragma unroll
    for (int kk=0;kk<16;kk++){
      float4 a0 = *(const float4*)(&As[kk][ty*8]);
      float4 a1 = *(const float4*)(&As[kk][ty*8+4]);
      float4 b0 = *(const float4*)(&Bs[kk][tx*8]);
      float4 b1 = *(const float4*)(&Bs[kk][tx*8+4]);
      float a[8] = {a0.x,a0.y,a0.z,a0.w,a1.x,a1.y,a1.z,a1.w};
      float b[8] = {b0.x,b0.y,b0.z,b0.w,b1.x,b1.y,b1.z,b1.w};
      #pragma unroll
      for (int i=0;i<8;i++)
        #pragma unroll
        for (int j=0;j<8;j++)
          acc[i][j] += a[i]*b[j];
    }
  }
  __syncthreads();
}

// ---------------- xp = [Q,Sub]@Wi[:,384:640].T + tables + bi ----------------
__global__ __launch_bounds__(256) void gemm_xp(const bf16* __restrict__ pred,
        const float* __restrict__ Wi, const float* __restrict__ bi,
        const float* __restrict__ Tans, const float* __restrict__ Tcae,
        const float* __restrict__ Tlab,
        const float* __restrict__ tm, const float* __restrict__ vm,
        const float* __restrict__ lm,
        const int* __restrict__ ans, const int* __restrict__ cans,
        const float* __restrict__ labels, float* __restrict__ xp){
  __shared__ float As[16][132]; __shared__ float Bs[16][132];
  float acc[8][8] = {{0.f}};
  int m0 = blockIdx.y*128, n0 = blockIdx.x*128;
  gemm_tile_bA(pred, PP, Wi+384, 640, 256, m0, n0, As, Bs, acc);
  int tx = threadIdx.x&15, ty = threadIdx.x>>4;
  #pragma unroll
  for (int i=0;i<8;i++){
    int r = m0 + ty*8 + i;
    float mk = tm[r]*vm[r]*lm[r];
    int a = ans[r], ca = cans[r], lb = (int)labels[r];
    #pragma unroll
    for (int j=0;j<8;j++){
      int c = n0 + tx*8 + j;
      xp[(size_t)r*G3 + c] = acc[i][j] + bi[c] + mk*Tans[a*G3+c] + Tcae[ca*G3+c] + mk*Tlab[lb*G3+c];
    }
  }
}

// ---------------- GRU scan: one block per batch element ----------------
// Wh rows register-resident (128 VGPR/thread); xp row prefetched one step ahead.
__global__ __launch_bounds__(384, 1) void gru_scan(const float* __restrict__ xp,
        const float* __restrict__ Wh, const float* __restrict__ bh,
        bf16* __restrict__ pred){
  __shared__ float hs[HH];
  __shared__ float gh[G3];
  int b = blockIdx.x;
  int tid = threadIdx.x;
  if (tid < HH) hs[tid] = 0.f;
  // hoist Wh row into registers (once)
  float4 w[32];
  const float4* wr = (const float4*)(Wh + (size_t)tid*HH);
  #pragma unroll
  for (int i=0;i<32;i++) w[i] = wr[i];
  float bhv = bh[tid];
  // prefetch t=0 x-row gates
  float xr=0.f, xz=0.f, xn=0.f;
  if (tid < HH){
    const float* xrow = xp + (size_t)b*G3;
    xr = xrow[tid]; xz = xrow[HH+tid]; xn = xrow[2*HH+tid];
  }
  __syncthreads();
  for (int t=0;t<SS;t++){
    // prefetch next step's x-row (hides HBM latency under the dot below)
    float nxr=0.f, nxz=0.f, nxn=0.f;
    if (tid < HH && t+1 < SS){
      const float* xrow = xp + (size_t)((t+1)*BB + b)*G3;
      nxr = xrow[tid]; nxz = xrow[HH+tid]; nxn = xrow[2*HH+tid];
    }
    // gh = Wh @ h  (weights in regs, hs broadcast from LDS)
    float acc = bhv;
    #pragma unroll
    for (int k4=0;k4<32;k4++){
      float4 wv = w[k4];
      float4 hv = *(const float4*)(&hs[k4*4]);
      acc += wv.x*hv.x + wv.y*hv.y + wv.z*hv.z + wv.w*hv.w;
    }
    gh[tid] = acc;
    __syncthreads();
    if (tid < HH){
      float hprev = hs[tid];
      float r = sigf(xr + gh[tid]);
      float z = sigf(xz + gh[HH+tid]);
      float n = tanhf(xn + r*gh[2*HH+tid]);
      float hnew = (1.f - z)*n + z*hprev;
      pred[(size_t)(t*BB + b)*PP + 256 + tid] = __float2bfloat16(hprev);
      hs[tid] = hnew;
    }
    __syncthreads();
    xr=nxr; xz=nxz; xn=nxn;
  }
}

// ---------------- h1 = relu(pred@l1W.T + b) (bf16 out) ----------------
__global__ __launch_bounds__(256) void gemm_l1(const bf16* __restrict__ pred,
        const float* __restrict__ W, const float* __restrict__ bias,
        bf16* __restrict__ h1){
  __shared__ float As[16][132]; __shared__ float Bs[16][132];
  float acc[8][8] = {{0.f}};
  int m0 = blockIdx.y*128, n0 = blockIdx.x*128;
  gemm_tile_bA(pred, PP, W, PP, PP, m0, n0, As, Bs, acc);
  int tx = threadIdx.x&15, ty = threadIdx.x>>4;
  #pragma unroll
  for (int i=0;i<8;i++){
    int r = m0 + ty*8 + i;
    #pragma unroll
    for (int j=0;j<8;j++){
      int c = n0 + tx*8 + j;
      h1[(size_t)r*PP + c] = __float2bfloat16(fmaxf(acc[i][j] + bias[c], 0.f));
    }
  }
}

// ---------------- h2 tile + fused (h2+pred)@outW partial into logits ----------------
__global__ __launch_bounds__(256) void gemm_l2_logits(const bf16* __restrict__ h1,
        const float* __restrict__ W, const float* __restrict__ bias,
        const bf16* __restrict__ pred, const float* __restrict__ outW,
        float* __restrict__ logits){
  __shared__ float As[16][132]; __shared__ float Bs[16][132];
  float acc[8][8] = {{0.f}};
  int m0 = blockIdx.y*128, n0 = blockIdx.x*128;
  gemm_tile_bA(h1, PP, W, PP, PP, m0, n0, As, Bs, acc);
  int tx = threadIdx.x&15, ty = threadIdx.x>>4;
  #pragma unroll
  for (int i=0;i<8;i++){
    int r = m0 + ty*8 + i;
    float part = 0.f;
    #pragma unroll
    for (int j=0;j<8;j++){
      int c = n0 + tx*8 + j;
      float h2v = fmaxf(acc[i][j] + bias[c], 0.f);
      part += (h2v + __bfloat162float(pred[(size_t)r*PP+c]))*outW[c];
    }
    part += __shfl_xor(part,1);
    part += __shfl_xor(part,2);
    part += __shfl_xor(part,4);
    part += __shfl_xor(part,8);
    if (tx==0) atomicAdd(&logits[r], part);
  }
}

// ---------------- loss + probs ----------------
__global__ __launch_bounds__(256) void loss_probs_k(const float* __restrict__ logits,
        const float* __restrict__ labels, const float* __restrict__ tm,
        const float* __restrict__ vm, const float* __restrict__ lm,
        const float* __restrict__ out_b, float* __restrict__ out,
        float* __restrict__ lacc){
  int i = blockIdx.x*256 + threadIdx.x;
  float x = logits[i] + out_b[0];
  float lb = labels[i];
  float mk = tm[i]*vm[i]*lm[i];
  float sp = fmaxf(x,0.f) + log1pf(expf(-fabsf(x)));
  float pe = (sp - x*lb)*mk;
  out[1+i] = sigf(x);
  float v0 = pe, v1 = mk;
  for (int o=32;o>0;o>>=1){ v0 += __shfl_down(v0,o); v1 += __shfl_down(v1,o); }
  if ((threadIdx.x & 63)==0){ atomicAdd(&lacc[0], v0); atomicAdd(&lacc[1], v1); }
}

__global__ void finalize_k(const float* __restrict__ lacc, float* __restrict__ out){
  out[0] = lacc[0]/lacc[1];
}

// ---------------- launch ----------------
extern "C" void kernel_launch(void* const* d_in, const int* in_sizes, int n_in,
                              void* d_out, int out_size, void* d_ws, size_t ws_size,
                              hipStream_t stream) {
  const float* q_emb   = (const float*)d_in[0];
  const float* s_emb   = (const float*)d_in[1];
  const float* ans_emb = (const float*)d_in[2];
  const float* lab_emb = (const float*)d_in[3];
  const float* gru_Wi  = (const float*)d_in[4];
  const float* gru_Wh  = (const float*)d_in[5];
  const float* gru_bi  = (const float*)d_in[6];
  const float* gru_bh  = (const float*)d_in[7];
  const float* s2s_W   = (const float*)d_in[8];
  const float* s2s_b   = (const float*)d_in[9];
  const float* s2q_W   = (const float*)d_in[10];
  const float* s2q_b   = (const float*)d_in[11];
  const float* q2q_W   = (const float*)d_in[12];
  const float* q2q_b   = (const float*)d_in[13];
  const float* q2s_W   = (const float*)d_in[14];
  const float* q2s_b   = (const float*)d_in[15];
  const float* l1_W    = (const float*)d_in[16];
  const float* l1_b    = (const float*)d_in[17];
  const float* l2_W    = (const float*)d_in[18];
  const float* l2_b    = (const float*)d_in[19];
  const float* out_W   = (const float*)d_in[20];
  const float* out_b   = (const float*)d_in[21];
  const float* tm      = (const float*)d_in[22];
  const float* vm      = (const float*)d_in[23];
  const float* lm      = (const float*)d_in[24];
  const float* smask   = (const float*)d_in[25];
  const float* q_mask  = (const float*)d_in[26];
  const float* labels  = (const float*)d_in[27];
  const int*   ans     = (const int*)d_in[28];
  const int*   cans    = (const int*)d_in[29];
  const int*   sub_ids = (const int*)d_in[30];
  const int*   q_ids   = (const int*)d_in[31];
  const int*   q_map   = (const int*)d_in[32];

  // ---- workspace layout (byte offsets, 256B-aligned) ----
  char* wsb = (char*)d_ws;
  size_t off = 0;
  auto alloc = [&](size_t bytes) -> char* {
    char* p = wsb + off;
    off += (bytes + 255) & ~(size_t)255;
    return p;
  };
  float* sums   = (float*)alloc(51200*4);        // [Ns,D]
  float* cnts   = (float*)alloc(400*4);
  float* subj1  = (float*)alloc(51200*4);        // [Ns,D] f32
  float* Tans   = (float*)alloc(4*G3*4);
  float* Tcae   = (float*)alloc(4*G3*4);
  float* Tlab   = (float*)alloc(2*G3*4);
  float* lacc   = (float*)alloc(2*4);
  float* logits = (float*)alloc((size_t)SB*4);
  bf16*  q1     = (bf16*) alloc((size_t)NQ*DD*2);        // 7.68 MB
  bf16*  pred   = (bf16*) alloc((size_t)SB*PP*2);        // 52.4 MB
  char*  xh     = alloc((size_t)SB*G3*4);                // 78.6 MB: xp f32, then h1 bf16
  float* xp     = (float*)xh;
  bf16*  h1     = (bf16*)xh;   // aliased: xp dead after gru_scan
  float* out    = (float*)d_out;

  hipMemsetAsync(sums, 0, (51200+400)*sizeof(float), stream);
  hipMemsetAsync(lacc, 0, 2*sizeof(float), stream);
  hipMemsetAsync(logits, 0, (size_t)SB*sizeof(float), stream);

  tables_k<<<dim3(3), dim3(128), 0, stream>>>(ans_emb, lab_emb, gru_Wi, Tans, Tcae, Tlab);
  q2s_scatter<<<dim3(NQ/QPB), dim3(128), 0, stream>>>(q_emb, q2s_W, q2s_b, q_map, sums, cnts);
  subjects1_k<<<dim3(NS), dim3(128), 0, stream>>>(s_emb, s2s_W, s2s_b, sums, cnts, subj1);
  questions1_k<<<dim3(NQ/QPB), dim3(128), 0, stream>>>(q_emb, subj1, q_map, q_mask,
                                                       s2q_W, s2q_b, q2q_W, q2q_b, q1);
  assemble_k<<<dim3(SB), dim3(128), 0, stream>>>(q1, subj1, ans_emb, cans, sub_ids, smask, q_ids, pred);
  gemm_xp<<<dim3(3,400), dim3(256), 0, stream>>>(pred, gru_Wi, gru_bi, Tans, Tcae, Tlab,
                                                 tm, vm, lm, ans, cans, labels, xp);
  gru_scan<<<dim3(BB), dim3(384), 0, stream>>>(xp, gru_Wh, gru_bh, pred);
  gemm_l1<<<dim3(4,400), dim3(256), 0, stream>>>(pred, l1_W, l1_b, h1);
  gemm_l2_logits<<<dim3(4,400), dim3(256), 0, stream>>>(h1, l2_W, l2_b, pred, out_W, logits);
  loss_probs_k<<<dim3(SB/256), dim3(256), 0, stream>>>(logits, labels, tm, vm, lm, out_b, out, lacc);
  finalize_k<<<dim3(1), dim3(1), 0, stream>>>(lacc, out);
}

// Round 4
// 1019.386 us; speedup vs baseline: 2.3271x; 1.3899x over previous
//
#include <hip/hip_runtime.h>
#include <hip/hip_bf16.h>
#include <math.h>

#define NQ 30000
#define NS 400
#define DD 128
#define HH 128
#define SS 200
#define BB 256
#define MSq 4
#define MBs 4
#define PP 512
#define SB (SS*BB)      // 51200
#define G3 384          // 3*H
#define QPB 16

typedef __hip_bfloat16 bf16;
typedef __attribute__((ext_vector_type(8))) short bf16x8;
typedef __attribute__((ext_vector_type(4))) float f32x4;

__device__ __forceinline__ float sigf(float x){ return 1.0f/(1.0f+expf(-x)); }
__device__ __forceinline__ float bf2f(unsigned short u){
  unsigned int x = ((unsigned int)u)<<16;
  return __uint_as_float(x);
}

// ---------------- tables: T_ans = ans_emb @ Wi[:,0:128].T etc ----------------
__global__ __launch_bounds__(128) void tables_k(const float* __restrict__ ans_emb,
        const float* __restrict__ label_emb, const float* __restrict__ Wi,
        float* __restrict__ Tans, float* __restrict__ Tcae, float* __restrict__ Tlab){
  int j = blockIdx.x*128 + threadIdx.x;
  if (j >= G3) return;
  const float* wr = Wi + (size_t)j*640;
  for (int a=0;a<4;a++){
    float acc=0.f;
    for (int k=0;k<DD;k++) acc += ans_emb[a*DD+k]*wr[k];
    Tans[a*G3+j]=acc;
  }
  for (int a=0;a<4;a++){
    float acc=0.f;
    for (int k=0;k<DD;k++) acc += ans_emb[a*DD+k]*wr[128+k];
    Tcae[a*G3+j]=acc;
  }
  for (int l=0;l<2;l++){
    float acc=0.f;
    for (int k=0;k<DD;k++) acc += label_emb[l*DD+k]*wr[256+k];
    Tlab[l*G3+j]=acc;
  }
}

// ---------------- weight convert: f32 -> bf16 ----------------
__global__ __launch_bounds__(256) void conv_w_k(const float* __restrict__ l1W,
        const float* __restrict__ l2W, const float* __restrict__ Wi,
        bf16* __restrict__ l1Wb, bf16* __restrict__ l2Wb, bf16* __restrict__ WiB){
  int i = blockIdx.x*256 + threadIdx.x;
  if (i < 512*512){
    l1Wb[i] = __float2bfloat16(l1W[i]);
    l2Wb[i] = __float2bfloat16(l2W[i]);
  }
  if (i < 384*256){
    int j = i >> 8, k = i & 255;
    WiB[i] = __float2bfloat16(Wi[j*640 + 384 + k]);
  }
}

// ---------------- q2s projection + scatter to subject sums ----------------
__global__ __launch_bounds__(128) void q2s_scatter(const float* __restrict__ q_emb,
        const float* __restrict__ W, const float* __restrict__ bias,
        const int* __restrict__ q_map, float* __restrict__ sums, float* __restrict__ cnts){
  __shared__ float qe[QPB][DD];
  int q0 = blockIdx.x*QPB;
  int tid = threadIdx.x;
  for (int r=0;r<QPB;r++) qe[r][tid] = q_emb[(size_t)(q0+r)*DD + tid];
  __syncthreads();
  float acc[QPB];
  #pragma unroll
  for (int r=0;r<QPB;r++) acc[r] = bias[tid];
  const float4* wr = (const float4*)(W + (size_t)tid*DD);
  #pragma unroll 4
  for (int k4=0;k4<DD/4;k4++){
    float4 w = wr[k4];
    #pragma unroll
    for (int r=0;r<QPB;r++){
      acc[r] += w.x*qe[r][k4*4] + w.y*qe[r][k4*4+1] + w.z*qe[r][k4*4+2] + w.w*qe[r][k4*4+3];
    }
  }
  for (int r=0;r<QPB;r++){
    int q = q0+r;
    #pragma unroll
    for (int m=0;m<MSq;m++){
      int s = q_map[q*MSq+m];
      atomicAdd(&sums[(size_t)s*DD + tid], acc[r]);
      if (tid==0) atomicAdd(&cnts[s], 1.0f);
    }
  }
}

// ---------------- subjects_1 ----------------
__global__ __launch_bounds__(128) void subjects1_k(const float* __restrict__ s_emb,
        const float* __restrict__ W, const float* __restrict__ bias,
        const float* __restrict__ sums, const float* __restrict__ cnts,
        float* __restrict__ out){
  __shared__ float se[DD];
  int s = blockIdx.x; int tid = threadIdx.x;
  se[tid] = s_emb[(size_t)s*DD+tid];
  __syncthreads();
  float acc = bias[tid];
  const float4* wr = (const float4*)(W + (size_t)tid*DD);
  for (int k4=0;k4<DD/4;k4++){
    float4 w = wr[k4];
    acc += w.x*se[k4*4] + w.y*se[k4*4+1] + w.z*se[k4*4+2] + w.w*se[k4*4+3];
  }
  float c = cnts[s];
  float v = 0.f;
  if (c > 0.f) v = tanhf(sums[(size_t)s*DD+tid]/fmaxf(c,1.f) + acc);
  out[(size_t)s*DD+tid] = v;
}

// ---------------- questions_1 (bf16 out) ----------------
__global__ __launch_bounds__(128) void questions1_k(const float* __restrict__ q_emb,
        const float* __restrict__ subj1, const int* __restrict__ q_map,
        const float* __restrict__ q_mask,
        const float* __restrict__ s2qW, const float* __restrict__ s2qb,
        const float* __restrict__ q2qW, const float* __restrict__ q2qb,
        bf16* __restrict__ q1out){
  __shared__ float qe[QPB][DD];
  __shared__ float nq[QPB][DD];
  int q0 = blockIdx.x*QPB; int tid = threadIdx.x;
  for (int r=0;r<QPB;r++){
    int q = q0+r;
    qe[r][tid] = q_emb[(size_t)q*DD+tid];
    float sum=0.f, wsum=0.f;
    #pragma unroll
    for (int m=0;m<MSq;m++){
      float w = q_mask[q*MSq+m];
      sum += subj1[(size_t)q_map[q*MSq+m]*DD + tid]*w;
      wsum += w;
    }
    nq[r][tid] = sum / wsum;
  }
  __syncthreads();
  float acc[QPB];
  #pragma unroll
  for (int r=0;r<QPB;r++) acc[r] = s2qb[tid]+q2qb[tid];
  const float4* w1 = (const float4*)(s2qW + (size_t)tid*DD);
  const float4* w2 = (const float4*)(q2qW + (size_t)tid*DD);
  #pragma unroll 2
  for (int k4=0;k4<DD/4;k4++){
    float4 a = w1[k4]; float4 b = w2[k4];
    #pragma unroll
    for (int r=0;r<QPB;r++){
      acc[r] += a.x*nq[r][k4*4] + a.y*nq[r][k4*4+1] + a.z*nq[r][k4*4+2] + a.w*nq[r][k4*4+3]
              + b.x*qe[r][k4*4] + b.y*qe[r][k4*4+1] + b.z*qe[r][k4*4+2] + b.w*qe[r][k4*4+3];
    }
  }
  for (int r=0;r<QPB;r++) q1out[(size_t)(q0+r)*DD+tid] = __float2bfloat16(tanhf(acc[r]));
}

// ---------------- assemble pred_input cols 0:256 and 384:512 (bf16) ----------------
__global__ __launch_bounds__(128) void assemble_k(const bf16* __restrict__ q1,
        const float* __restrict__ subj1, const float* __restrict__ ans_emb,
        const int* __restrict__ cans, const int* __restrict__ sub_ids,
        const float* __restrict__ sub_mask, const int* __restrict__ q_ids,
        bf16* __restrict__ pred){
  int i = blockIdx.x; int d = threadIdx.x;
  size_t base = (size_t)i*PP;
  pred[base + d] = q1[(size_t)q_ids[i]*DD + d];
  float s = 0.f;
  #pragma unroll
  for (int m=0;m<MBs;m++)
    s += subj1[(size_t)sub_ids[i*MBs+m]*DD+d]*sub_mask[i*MBs+m];
  pred[base+128+d] = __float2bfloat16(s);
  pred[base+384+d] = __float2bfloat16(ans_emb[(size_t)cans[i]*DD + d]);
}

// ======== MFMA GEMM core: C[128x128] tile = A[128xK] @ Bw[128xK]^T ========
// A row-major bf16 (lda elements), Bw row-major bf16 [n][k] (ldb elements).
// 256 threads = 4 waves in 2x2 grid; each wave 64x64 = 4x4 fragments of 16x16.
// Fragments loaded directly from global (no LDS, no barriers -> compiler pipelines).
// Layouts (m89/m97-verified): A/B frag: lane&15 = row(col), k = (lane>>4)*8+j.
// C/D: col = lane&15, row = (lane>>4)*4 + reg.
#define MFMA_CORE(A_, lda_, B_, ldb_, K_) \
  int lane = threadIdx.x & 63; int wid = threadIdx.x >> 6; \
  int wy = wid >> 1, wx = wid & 1; \
  int mbase = blockIdx.x*128 + wy*64; \
  int nbase = blockIdx.y*128 + wx*64; \
  int lr = lane & 15, kg = (lane >> 4) * 8; \
  f32x4 acc[4][4]; \
  _Pragma("unroll") for (int i=0;i<4;i++) _Pragma("unroll") for (int j=0;j<4;j++) acc[i][j] = (f32x4){0.f,0.f,0.f,0.f}; \
  for (int k=0; k<(K_); k+=32){ \
    bf16x8 af[4], bfr[4]; \
    _Pragma("unroll") for (int mi=0;mi<4;mi++) \
      af[mi] = *(const bf16x8*)((A_) + (size_t)(mbase+mi*16+lr)*(lda_) + k + kg); \
    _Pragma("unroll") for (int ni=0;ni<4;ni++) \
      bfr[ni] = *(const bf16x8*)((B_) + (size_t)(nbase+ni*16+lr)*(ldb_) + k + kg); \
    _Pragma("unroll") for (int mi=0;mi<4;mi++) \
      _Pragma("unroll") for (int ni=0;ni<4;ni++) \
        acc[mi][ni] = __builtin_amdgcn_mfma_f32_16x16x32_bf16(af[mi], bfr[ni], acc[mi][ni], 0, 0, 0); \
  }

// ---------------- xp = pred[:,0:256]@WiB.T + tables + bi ----------------
__global__ __launch_bounds__(256) void gemm_xp(const bf16* __restrict__ pred,
        const bf16* __restrict__ WiB, const float* __restrict__ bi,
        const float* __restrict__ Tans, const float* __restrict__ Tcae,
        const float* __restrict__ Tlab,
        const float* __restrict__ tm, const float* __restrict__ vm,
        const float* __restrict__ lm,
        const int* __restrict__ ans, const int* __restrict__ cans,
        const float* __restrict__ labels, float* __restrict__ xp){
  MFMA_CORE(pred, PP, WiB, 256, 256)
  #pragma unroll
  for (int mi=0;mi<4;mi++){
    #pragma unroll
    for (int r=0;r<4;r++){
      int row = mbase + mi*16 + (lane>>4)*4 + r;
      float mk = tm[row]*vm[row]*lm[row];
      int a = ans[row], ca = cans[row], lb = (int)labels[row];
      #pragma unroll
      for (int ni=0;ni<4;ni++){
        int c = nbase + ni*16 + lr;
        xp[(size_t)row*G3 + c] = acc[mi][ni][r] + bi[c]
            + mk*Tans[a*G3+c] + Tcae[ca*G3+c] + mk*Tlab[lb*G3+c];
      }
    }
  }
}

// ---------------- h1 = relu(pred@l1W.T + b) (bf16 out) ----------------
__global__ __launch_bounds__(256) void gemm_l1(const bf16* __restrict__ pred,
        const bf16* __restrict__ Wb, const float* __restrict__ bias,
        bf16* __restrict__ h1){
  MFMA_CORE(pred, PP, Wb, PP, PP)
  #pragma unroll
  for (int mi=0;mi<4;mi++){
    #pragma unroll
    for (int ni=0;ni<4;ni++){
      int c = nbase + ni*16 + lr;
      float bia = bias[c];
      #pragma unroll
      for (int r=0;r<4;r++){
        int row = mbase + mi*16 + (lane>>4)*4 + r;
        h1[(size_t)row*PP + c] = __float2bfloat16(fmaxf(acc[mi][ni][r] + bia, 0.f));
      }
    }
  }
}

// ---------------- h2 tile + fused (h2+pred)@outW partial into logits ----------------
__global__ __launch_bounds__(256) void gemm_l2_logits(const bf16* __restrict__ h1,
        const bf16* __restrict__ Wb, const float* __restrict__ bias,
        const bf16* __restrict__ pred, const float* __restrict__ outW,
        float* __restrict__ logits){
  MFMA_CORE(h1, PP, Wb, PP, PP)
  #pragma unroll
  for (int mi=0;mi<4;mi++){
    #pragma unroll
    for (int r=0;r<4;r++){
      int row = mbase + mi*16 + (lane>>4)*4 + r;
      float p = 0.f;
      #pragma unroll
      for (int ni=0;ni<4;ni++){
        int c = nbase + ni*16 + lr;
        float h2v = fmaxf(acc[mi][ni][r] + bias[c], 0.f);
        p += (h2v + __bfloat162float(pred[(size_t)row*PP + c])) * outW[c];
      }
      p += __shfl_xor(p,1);
      p += __shfl_xor(p,2);
      p += __shfl_xor(p,4);
      p += __shfl_xor(p,8);
      if (lr == 0) atomicAdd(&logits[row], p);
    }
  }
}

// ---------------- GRU scan: one block per batch element ----------------
__global__ __launch_bounds__(384, 1) void gru_scan(const float* __restrict__ xp,
        const float* __restrict__ Wh, const float* __restrict__ bh,
        bf16* __restrict__ pred){
  __shared__ float hs[HH];
  __shared__ float gh[G3];
  int b = blockIdx.x;
  int tid = threadIdx.x;
  if (tid < HH) hs[tid] = 0.f;
  float4 w[32];
  const float4* wr = (const float4*)(Wh + (size_t)tid*HH);
  #pragma unroll
  for (int i=0;i<32;i++) w[i] = wr[i];
  float bhv = bh[tid];
  float xr=0.f, xz=0.f, xn=0.f;
  if (tid < HH){
    const float* xrow = xp + (size_t)b*G3;
    xr = xrow[tid]; xz = xrow[HH+tid]; xn = xrow[2*HH+tid];
  }
  __syncthreads();
  for (int t=0;t<SS;t++){
    float nxr=0.f, nxz=0.f, nxn=0.f;
    if (tid < HH && t+1 < SS){
      const float* xrow = xp + (size_t)((t+1)*BB + b)*G3;
      nxr = xrow[tid]; nxz = xrow[HH+tid]; nxn = xrow[2*HH+tid];
    }
    float acc = bhv;
    #pragma unroll
    for (int k4=0;k4<32;k4++){
      float4 wv = w[k4];
      float4 hv = *(const float4*)(&hs[k4*4]);
      acc += wv.x*hv.x + wv.y*hv.y + wv.z*hv.z + wv.w*hv.w;
    }
    gh[tid] = acc;
    __syncthreads();
    if (tid < HH){
      float hprev = hs[tid];
      float r = sigf(xr + gh[tid]);
      float z = sigf(xz + gh[HH+tid]);
      float n = tanhf(xn + r*gh[2*HH+tid]);
      float hnew = (1.f - z)*n + z*hprev;
      pred[(size_t)(t*BB + b)*PP + 256 + tid] = __float2bfloat16(hprev);
      hs[tid] = hnew;
    }
    __syncthreads();
    xr=nxr; xz=nxz; xn=nxn;
  }
}

// ---------------- loss + probs ----------------
__global__ __launch_bounds__(256) void loss_probs_k(const float* __restrict__ logits,
        const float* __restrict__ labels, const float* __restrict__ tm,
        const float* __restrict__ vm, const float* __restrict__ lm,
        const float* __restrict__ out_b, float* __restrict__ out,
        float* __restrict__ lacc){
  int i = blockIdx.x*256 + threadIdx.x;
  float x = logits[i] + out_b[0];
  float lb = labels[i];
  float mk = tm[i]*vm[i]*lm[i];
  float sp = fmaxf(x,0.f) + log1pf(expf(-fabsf(x)));
  float pe = (sp - x*lb)*mk;
  out[1+i] = sigf(x);
  float v0 = pe, v1 = mk;
  for (int o=32;o>0;o>>=1){ v0 += __shfl_down(v0,o); v1 += __shfl_down(v1,o); }
  if ((threadIdx.x & 63)==0){ atomicAdd(&lacc[0], v0); atomicAdd(&lacc[1], v1); }
}

__global__ void finalize_k(const float* __restrict__ lacc, float* __restrict__ out){
  out[0] = lacc[0]/lacc[1];
}

// ---------------- launch ----------------
extern "C" void kernel_launch(void* const* d_in, const int* in_sizes, int n_in,
                              void* d_out, int out_size, void* d_ws, size_t ws_size,
                              hipStream_t stream) {
  const float* q_emb   = (const float*)d_in[0];
  const float* s_emb   = (const float*)d_in[1];
  const float* ans_emb = (const float*)d_in[2];
  const float* lab_emb = (const float*)d_in[3];
  const float* gru_Wi  = (const float*)d_in[4];
  const float* gru_Wh  = (const float*)d_in[5];
  const float* gru_bi  = (const float*)d_in[6];
  const float* gru_bh  = (const float*)d_in[7];
  const float* s2s_W   = (const float*)d_in[8];
  const float* s2s_b   = (const float*)d_in[9];
  const float* s2q_W   = (const float*)d_in[10];
  const float* s2q_b   = (const float*)d_in[11];
  const float* q2q_W   = (const float*)d_in[12];
  const float* q2q_b   = (const float*)d_in[13];
  const float* q2s_W   = (const float*)d_in[14];
  const float* q2s_b   = (const float*)d_in[15];
  const float* l1_W    = (const float*)d_in[16];
  const float* l1_b    = (const float*)d_in[17];
  const float* l2_W    = (const float*)d_in[18];
  const float* l2_b    = (const float*)d_in[19];
  const float* out_W   = (const float*)d_in[20];
  const float* out_b   = (const float*)d_in[21];
  const float* tm      = (const float*)d_in[22];
  const float* vm      = (const float*)d_in[23];
  const float* lm      = (const float*)d_in[24];
  const float* smask   = (const float*)d_in[25];
  const float* q_mask  = (const float*)d_in[26];
  const float* labels  = (const float*)d_in[27];
  const int*   ans     = (const int*)d_in[28];
  const int*   cans    = (const int*)d_in[29];
  const int*   sub_ids = (const int*)d_in[30];
  const int*   q_ids   = (const int*)d_in[31];
  const int*   q_map   = (const int*)d_in[32];

  // ---- workspace layout (byte offsets, 256B-aligned) ----
  char* wsb = (char*)d_ws;
  size_t off = 0;
  auto alloc = [&](size_t bytes) -> char* {
    char* p = wsb + off;
    off += (bytes + 255) & ~(size_t)255;
    return p;
  };
  float* sums   = (float*)alloc(51200*4);        // [Ns,D]
  float* cnts   = (float*)alloc(400*4);
  float* subj1  = (float*)alloc(51200*4);        // [Ns,D] f32
  float* Tans   = (float*)alloc(4*G3*4);
  float* Tcae   = (float*)alloc(4*G3*4);
  float* Tlab   = (float*)alloc(2*G3*4);
  float* lacc   = (float*)alloc(2*4);
  float* logits = (float*)alloc((size_t)SB*4);
  bf16*  l1Wb   = (bf16*) alloc((size_t)512*512*2);
  bf16*  l2Wb   = (bf16*) alloc((size_t)512*512*2);
  bf16*  WiB    = (bf16*) alloc((size_t)384*256*2);
  bf16*  q1     = (bf16*) alloc((size_t)NQ*DD*2);        // 7.68 MB
  bf16*  pred   = (bf16*) alloc((size_t)SB*PP*2);        // 52.4 MB
  char*  xh     = alloc((size_t)SB*G3*4);                // 78.6 MB: xp f32, then h1 bf16
  float* xp     = (float*)xh;
  bf16*  h1     = (bf16*)xh;   // aliased: xp dead after gru_scan
  float* out    = (float*)d_out;

  hipMemsetAsync(sums, 0, (51200+400)*sizeof(float), stream);
  hipMemsetAsync(lacc, 0, 2*sizeof(float), stream);
  hipMemsetAsync(logits, 0, (size_t)SB*sizeof(float), stream);

  tables_k<<<dim3(3), dim3(128), 0, stream>>>(ans_emb, lab_emb, gru_Wi, Tans, Tcae, Tlab);
  conv_w_k<<<dim3(1024), dim3(256), 0, stream>>>(l1_W, l2_W, gru_Wi, l1Wb, l2Wb, WiB);
  q2s_scatter<<<dim3(NQ/QPB), dim3(128), 0, stream>>>(q_emb, q2s_W, q2s_b, q_map, sums, cnts);
  subjects1_k<<<dim3(NS), dim3(128), 0, stream>>>(s_emb, s2s_W, s2s_b, sums, cnts, subj1);
  questions1_k<<<dim3(NQ/QPB), dim3(128), 0, stream>>>(q_emb, subj1, q_map, q_mask,
                                                       s2q_W, s2q_b, q2q_W, q2q_b, q1);
  assemble_k<<<dim3(SB), dim3(128), 0, stream>>>(q1, subj1, ans_emb, cans, sub_ids, smask, q_ids, pred);
  // grid: x = m-blocks (fast-varying -> W panel stays L2-hot), y = n-blocks
  gemm_xp<<<dim3(400,3), dim3(256), 0, stream>>>(pred, WiB, gru_bi, Tans, Tcae, Tlab,
                                                 tm, vm, lm, ans, cans, labels, xp);
  gru_scan<<<dim3(BB), dim3(384), 0, stream>>>(xp, gru_Wh, gru_bh, pred);
  gemm_l1<<<dim3(400,4), dim3(256), 0, stream>>>(pred, l1Wb, l1_b, h1);
  gemm_l2_logits<<<dim3(400,4), dim3(256), 0, stream>>>(h1, l2Wb, l2_b, pred, out_W, logits);
  loss_probs_k<<<dim3(SB/256), dim3(256), 0, stream>>>(logits, labels, tm, vm, lm, out_b, out, lacc);
  finalize_k<<<dim3(1), dim3(1), 0, stream>>>(lacc, out);
}